// Round 18
// baseline (672.437 us; speedup 1.0000x reference)
//
#include <hip/hip_runtime.h>

typedef __attribute__((ext_vector_type(4))) float float4v;
typedef __attribute__((ext_vector_type(2))) float float2v;
typedef __attribute__((ext_vector_type(8))) short short8;
typedef __attribute__((ext_vector_type(4))) float f32x4;

#define NEGV (-1000000000.0f)

// B=64, L=2048, E=512, Q=256; M = 131072, K = 512, N = 512
#define MTOT (64 * 2048)

__device__ __forceinline__ unsigned short f2bf(float f) {
    unsigned int u = __float_as_uint(f);
    u += 0x7fffu + ((u >> 16) & 1u);   // RNE round to bf16
    return (unsigned short)(u >> 16);
}

// async global->LDS, 16B per lane; LDS dest = wave-uniform base + lane*16
__device__ __forceinline__ void gload_lds16(const void* g, void* l) {
    __builtin_amdgcn_global_load_lds(
        (__attribute__((address_space(1))) unsigned int*)(unsigned long long)(g),
        (__attribute__((address_space(3))) unsigned int*)(unsigned int)(unsigned long long)(l),
        16, 0, 0);
}

// Wt[e][c] = bf16(W1[c][e]) via LDS 32x32 tile transpose.
__global__ __launch_bounds__(256)
void prep_wt_kernel(const float* __restrict__ W1, unsigned short* __restrict__ Wt) {
    __shared__ float t[32][33];
    int bx = blockIdx.x & 15;    // c tile
    int by = blockIdx.x >> 4;    // e tile
    int tx = threadIdx.x & 31;
    int ty = threadIdx.x >> 5;   // 0..7
    #pragma unroll
    for (int i = 0; i < 4; ++i)
        t[ty + 8 * i][tx] = W1[(bx * 32 + ty + 8 * i) * 512 + by * 32 + tx];
    __syncthreads();
    #pragma unroll
    for (int i = 0; i < 4; ++i)
        Wt[(by * 32 + ty + 8 * i) * 512 + bx * 32 + tx] = f2bf(t[tx][ty + 8 * i]);
}

// qc[b][e] = b1[e] + sum_q query[b][q] * W1[512+q][e]; also zeroes ctxraw/S.
__global__ void prep_qc_kernel(const float* __restrict__ query, const float* __restrict__ W1,
                               const float* __restrict__ b1, float* __restrict__ qc,
                               float* __restrict__ ctxraw, float* __restrict__ S) {
    int b = blockIdx.x;
    int e = threadIdx.x;           // 256 threads -> cols e and e+256
    ctxraw[b * 512 + e] = 0.f;
    ctxraw[b * 512 + 256 + e] = 0.f;
    if (e == 0) S[b] = 0.f;
    float acc0 = b1[e];
    float acc1 = b1[e + 256];
    const float* w = W1 + 512 * 512;
    #pragma unroll 8
    for (int q = 0; q < 256; ++q) {
        float qv = query[b * 256 + q];
        acc0 += qv * w[q * 512 + e];
        acc1 += qv * w[q * 512 + e + 256];
    }
    qc[b * 512 + e] = acc0;
    qc[b * 512 + e + 256] = acc1;
}

// R17's fused gemm (BM=128 x BN=512, BK=32, 16 waves, dbuf-2) with LDS
// squeezed to EXACTLY 80KB -> 2 blocks/CU (32 waves/CU, max occupancy):
// lred/wbuf are overlaid on the As slot-0 region (dead after the last
// slot-0 read, which completes at KITER(14)'s closing barrier; KCOMP(1)
// only touches As slot 1 + Bs). One block's per-step drain now overlaps
// the sibling block's compute (m114 mechanism).
__global__ __launch_bounds__(1024, 8)
void gemm_fused_kernel(const float* __restrict__ A,             // encoded [M][512] f32
                       const unsigned short* __restrict__ Wt,   // [512 n][512 k] bf16
                       const float* __restrict__ qc,            // [64][512]
                       const float* __restrict__ v,             // [512]
                       const int* __restrict__ length,          // [64]
                       float* __restrict__ att,                 // [M] raw w out
                       float* __restrict__ ctxraw,              // [64][512] accum
                       float* __restrict__ S)                   // [64] sum accum
{
    int bm = blockIdx.x;           // 0..1023 row tile
    int b = bm >> 4;
    int len = length[b];
    int l0 = (bm & 15) * 128;
    if (l0 >= len) return;         // fully-masked tile

    __shared__ char smem[81920];   // 2 x 80KB = full 160KB LDS per CU
    unsigned short* As = (unsigned short*)smem;            // 2 x 8 KB (slots)
    unsigned short* Bs = (unsigned short*)(smem + 16384);  // 2 x 32 KB
    float (*lred)[8] = (float(*)[8])smem;                  // overlay on As slot0
    float* wbuf = (float*)(smem + 4096);                   // overlay on As slot0

    int tid = threadIdx.x;
    int lane = tid & 63;
    int w = tid >> 6;              // 0..15
    int wm = w >> 3, wn = w & 7;   // 2 x 8 wave grid; wave tile 64x64
    long row0 = (long)bm * 128;

    // --- A reg-staging: thread -> row r = tid>>3, k-eighth e8 = tid&7 (16B) ---
    int ar_r = tid >> 3;
    int ar_e = tid & 7;
    const char* gAr = (const char*)A + (row0 + ar_r) * 2048 + ar_e * 16;
    int awr = ar_r * 64 + ((ar_e * 8) ^ (((ar_r >> 1) & 3) << 4));

    // --- B staging: linear LDS dest (wave base + lane*16), pre-swizzled src ---
    int offw = w * 2048 + lane * 16;             // this wave's 2KB of 32KB slot
    const char* gB0;
    const char* gB1;
    {
        int o = offw;
        int r = o >> 6;
        gB0 = (const char*)Wt + r * 1024 + ((o & 63) ^ (((r >> 1) & 3) << 4));
        o = offw + 1024;
        r = o >> 6;
        gB1 = (const char*)Wt + r * 1024 + ((o & 63) ^ (((r >> 1) & 3) << 4));
    }

    // --- fragment read byte offsets (within one slot) ---
    int aoff[4], boff[4];
    int kb = 16 * (lane >> 4);
    #pragma unroll
    for (int mi = 0; mi < 4; ++mi) {
        int ar = wm * 64 + (lane & 15) + mi * 16;
        aoff[mi] = ar * 64 + (kb ^ (((ar >> 1) & 3) << 4));
    }
    #pragma unroll
    for (int ni = 0; ni < 4; ++ni) {
        int br = wn * 64 + (lane & 15) + ni * 16;
        boff[ni] = br * 64 + (kb ^ (((br >> 1) & 3) << 4));
    }

    f32x4 acc[4][4] = {};
    float4v P;

#define GISSUE(t, sI) do {                                                   \
    P = *(const float4v*)(gAr + (t) * 128);                                  \
    char* lb_ = (char*)Bs + (sI) * 32768 + offw;                             \
    gload_lds16(gB0 + (t) * 64, lb_);                                        \
    gload_lds16(gB1 + (t) * 64, lb_ + 1024);                                 \
} while (0)

#define CVTW(sW) do {                                                        \
    union { unsigned int u[2]; unsigned long long ll; } pk_;                 \
    pk_.u[0] = (unsigned int)f2bf(P[0]) | ((unsigned int)f2bf(P[1]) << 16);  \
    pk_.u[1] = (unsigned int)f2bf(P[2]) | ((unsigned int)f2bf(P[3]) << 16);  \
    *(unsigned long long*)((char*)As + (sW) * 8192 + awr) = pk_.ll;          \
} while (0)

#define KCOMP(sC) do {                                                       \
    const char* as_ = (const char*)As + (sC) * 8192;                         \
    const char* bs_ = (const char*)Bs + (sC) * 32768;                        \
    short8 af_[4];                                                           \
    _Pragma("unroll")                                                        \
    for (int mi = 0; mi < 4; ++mi) af_[mi] = *(const short8*)(as_ + aoff[mi]); \
    _Pragma("unroll")                                                        \
    for (int ni = 0; ni < 4; ++ni) {                                         \
        short8 bf_ = *(const short8*)(bs_ + boff[ni]);                       \
        _Pragma("unroll")                                                    \
        for (int mi = 0; mi < 4; ++mi)                                       \
            acc[mi][ni] = __builtin_amdgcn_mfma_f32_16x16x32_bf16(af_[mi], bf_, acc[mi][ni], 0, 0, 0); \
    }                                                                        \
} while (0)

#define KITER(t) do {                                                        \
    GISSUE((t) + 1, ((t) + 1) & 1);                                          \
    KCOMP((t) & 1);                                                          \
    asm volatile("s_waitcnt vmcnt(2)" ::: "memory");                         \
    CVTW(((t) + 1) & 1);                                                     \
    asm volatile("s_waitcnt vmcnt(0) lgkmcnt(0)" ::: "memory");              \
    __builtin_amdgcn_s_barrier();                                            \
    asm volatile("" ::: "memory");                                           \
} while (0)

    // prologue: stage K-step 0 into slot 0
    GISSUE(0, 0);
    asm volatile("s_waitcnt vmcnt(2)" ::: "memory");   // A regs landed
    CVTW(0);
    asm volatile("s_waitcnt vmcnt(0) lgkmcnt(0)" ::: "memory");
    __builtin_amdgcn_s_barrier();
    asm volatile("" ::: "memory");

    KITER(0);  KITER(1);  KITER(2);  KITER(3);
    KITER(4);  KITER(5);  KITER(6);  KITER(7);
    KITER(8);  KITER(9);  KITER(10); KITER(11);
    KITER(12); KITER(13); KITER(14);
    KCOMP(1);                                          // t = 15 (As slot1 + Bs only)

    // epilogue: u = tanh(acc + qc), per-wave 64-col partial via 16-lane
    // reduce, then in-block reduce over the 8 wn waves in LDS (overlaid).
    const float* qcb = qc + b * 512;
    float vcol[4], qcol[4];
    #pragma unroll
    for (int ni = 0; ni < 4; ++ni) {
        int c = wn * 64 + ni * 16 + (lane & 15);
        vcol[ni] = v[c];
        qcol[ni] = qcb[c];
    }
    #pragma unroll
    for (int mi = 0; mi < 4; ++mi) {
        #pragma unroll
        for (int j2 = 0; j2 < 4; ++j2) {
            float s = 0.f;
            #pragma unroll
            for (int ni = 0; ni < 4; ++ni) {
                float xx = acc[mi][ni][j2] + qcol[ni];
                float e2 = __expf(2.0f * xx);
                float tt = 1.0f - 2.0f * __builtin_amdgcn_rcpf(e2 + 1.0f);
                s += tt * vcol[ni];
            }
            s += __shfl_xor(s, 1);
            s += __shfl_xor(s, 2);
            s += __shfl_xor(s, 4);
            s += __shfl_xor(s, 8);
            if ((lane & 15) == 0)
                lred[wm * 64 + mi * 16 + 4 * (lane >> 4) + j2][wn] = s;
        }
    }
    __syncthreads();

    // fused: w = exp(logit) (0 beyond length), raw w -> att, sum -> S[b]
    if (tid < 128) {
        float lg = 0.f;
        #pragma unroll
        for (int q = 0; q < 8; ++q) lg += lred[tid][q];
        float wf = (l0 + tid < len) ? __expf(lg) : 0.f;
        att[row0 + tid] = wf;
        wbuf[tid] = wf;
        float s = wf;
        #pragma unroll
        for (int m = 32; m; m >>= 1) s += __shfl_xor(s, m);
        if ((tid & 63) == 0) atomicAdd(&S[b], s);
    }
    __syncthreads();

    // fused ctx: thread covers e = tid&511, l-half = tid>>9 (L2-hot A tile)
    {
        int e = tid & 511;
        int lh = tid >> 9;                 // 0 or 1
        const float* encb = A + (row0 + lh * 64) * 512 + e;
        const float* wb = &wbuf[lh * 64];
        float c = 0.f;
        #pragma unroll 4
        for (int l = 0; l < 64; ++l)
            c += wb[l] * encb[l * 512];
        atomicAdd(&ctxraw[b * 512 + e], c);
    }
}

// normalize: att[l] = (l<len) ? w[l]/S[b] : 0 ; ctx = ctxraw/S[b]
__global__ void norm_kernel(const float* __restrict__ S, const int* __restrict__ length,
                            const float* __restrict__ ctxraw,
                            float* __restrict__ att, float* __restrict__ ctx) {
    int b = blockIdx.x;
    int tid = threadIdx.x;     // 256
    float inv = 1.0f / S[b];
    ctx[b * 512 + tid] = ctxraw[b * 512 + tid] * inv;
    ctx[b * 512 + 256 + tid] = ctxraw[b * 512 + 256 + tid] * inv;
    int len = length[b];
    float* ab = att + b * 2048;
    #pragma unroll
    for (int i = 0; i < 8; ++i) {
        int l = tid + i * 256;
        float wv = ab[l];
        ab[l] = (l < len) ? wv * inv : 0.f;
    }
}

extern "C" void kernel_launch(void* const* d_in, const int* in_sizes, int n_in,
                              void* d_out, int out_size, void* d_ws, size_t ws_size,
                              hipStream_t stream) {
    const float* enc    = (const float*)d_in[0];   // [64,2048,512]
    const float* query  = (const float*)d_in[1];   // [64,256]
    const int*   length = (const int*)d_in[2];     // [64]
    const float* W1     = (const float*)d_in[3];   // [768,512]
    const float* b1     = (const float*)d_in[4];   // [512]
    const float* v      = (const float*)d_in[5];   // [512]

    float* out = (float*)d_out;
    float* ctx = out;                // [64,512]
    float* att = out + 64 * 512;     // [64,2048]

    char* ws = (char*)d_ws;
    float* qc          = (float*)ws;                               // 128KB
    unsigned short* Wt = (unsigned short*)(ws + 64 * 512 * 4);     // 512KB
    float* ctxraw      = (float*)(ws + 64 * 512 * 4 + 512 * 1024); // 128KB
    float* S           = (float*)(ws + 64 * 512 * 4 + 512 * 1024 + 64 * 512 * 4); // 256B

    prep_wt_kernel<<<256, 256, 0, stream>>>(W1, Wt);
    prep_qc_kernel<<<64, 256, 0, stream>>>(query, W1, b1, qc, ctxraw, S);

    gemm_fused_kernel<<<1024, 1024, 0, stream>>>(enc, Wt, qc, v, length, att, ctxraw, S);

    norm_kernel<<<64, 256, 0, stream>>>(S, length, ctxraw, att, ctx);
}

// Round 19
// 139.896 us; speedup vs baseline: 4.8067x; 4.8067x over previous
//
#include <hip/hip_runtime.h>

typedef __attribute__((ext_vector_type(4))) float float4v;
typedef __attribute__((ext_vector_type(2))) float float2v;
typedef __attribute__((ext_vector_type(8))) short short8;
typedef __attribute__((ext_vector_type(4))) float f32x4;

#define NEGV (-1000000000.0f)

// B=64, L=2048, E=512, Q=256; M = 131072, K = 512, N = 512
#define MTOT (64 * 2048)

__device__ __forceinline__ unsigned short f2bf(float f) {
    unsigned int u = __float_as_uint(f);
    u += 0x7fffu + ((u >> 16) & 1u);   // RNE round to bf16
    return (unsigned short)(u >> 16);
}

// async global->LDS, 16B per lane; LDS dest = wave-uniform base + lane*16
__device__ __forceinline__ void gload_lds16(const void* g, void* l) {
    __builtin_amdgcn_global_load_lds(
        (__attribute__((address_space(1))) unsigned int*)(unsigned long long)(g),
        (__attribute__((address_space(3))) unsigned int*)(unsigned int)(unsigned long long)(l),
        16, 0, 0);
}

// Wt[e][c] = bf16(W1[c][e]) via LDS 32x32 tile transpose.
__global__ __launch_bounds__(256)
void prep_wt_kernel(const float* __restrict__ W1, unsigned short* __restrict__ Wt) {
    __shared__ float t[32][33];
    int bx = blockIdx.x & 15;    // c tile
    int by = blockIdx.x >> 4;    // e tile
    int tx = threadIdx.x & 31;
    int ty = threadIdx.x >> 5;   // 0..7
    #pragma unroll
    for (int i = 0; i < 4; ++i)
        t[ty + 8 * i][tx] = W1[(bx * 32 + ty + 8 * i) * 512 + by * 32 + tx];
    __syncthreads();
    #pragma unroll
    for (int i = 0; i < 4; ++i)
        Wt[(by * 32 + ty + 8 * i) * 512 + bx * 32 + tx] = f2bf(t[tx][ty + 8 * i]);
}

// qc[b][e] = b1[e] + sum_q query[b][q] * W1[512+q][e]; also zeroes ctxraw/S.
__global__ void prep_qc_kernel(const float* __restrict__ query, const float* __restrict__ W1,
                               const float* __restrict__ b1, float* __restrict__ qc,
                               float* __restrict__ ctxraw, float* __restrict__ S) {
    int b = blockIdx.x;
    int e = threadIdx.x;           // 256 threads -> cols e and e+256
    ctxraw[b * 512 + e] = 0.f;
    ctxraw[b * 512 + 256 + e] = 0.f;
    if (e == 0) S[b] = 0.f;
    float acc0 = b1[e];
    float acc1 = b1[e + 256];
    const float* w = W1 + 512 * 512;
    #pragma unroll 8
    for (int q = 0; q < 256; ++q) {
        float qv = query[b * 256 + q];
        acc0 += qv * w[q * 512 + e];
        acc1 += qv * w[q * 512 + e + 256];
    }
    qc[b * 512 + e] = acc0;
    qc[b * 512 + e + 256] = acc1;
}

// R17's fused gemm (BM=128 x BN=512, BK=32, 16 waves, dbuf-2) with LDS
// squeezed to EXACTLY 80KB via lred/wbuf overlay on As slot-0. NO min-wave
// launch-bounds cap (R18's ",8" slashed VGPR 64->32 and spilled everything:
// FETCH 125->585MB). R17's body compiles to 64 VGPR naturally; 2 blocks x
// 16 waves x 64 VGPR x 64 lanes = 131072 = the full register file, and
// 2 x 81920B = the full 160KiB LDS -> hardware co-schedules 2 blocks/CU,
// one block's per-step drain overlapping the sibling's compute (m114).
__global__ __launch_bounds__(1024)
void gemm_fused_kernel(const float* __restrict__ A,             // encoded [M][512] f32
                       const unsigned short* __restrict__ Wt,   // [512 n][512 k] bf16
                       const float* __restrict__ qc,            // [64][512]
                       const float* __restrict__ v,             // [512]
                       const int* __restrict__ length,          // [64]
                       float* __restrict__ att,                 // [M] raw w out
                       float* __restrict__ ctxraw,              // [64][512] accum
                       float* __restrict__ S)                   // [64] sum accum
{
    int bm = blockIdx.x;           // 0..1023 row tile
    int b = bm >> 4;
    int len = length[b];
    int l0 = (bm & 15) * 128;
    if (l0 >= len) return;         // fully-masked tile

    __shared__ char smem[81920];   // 2 x 80KB = full 160KB LDS per CU
    unsigned short* As = (unsigned short*)smem;            // 2 x 8 KB (slots)
    unsigned short* Bs = (unsigned short*)(smem + 16384);  // 2 x 32 KB
    float (*lred)[8] = (float(*)[8])smem;                  // overlay on As slot0
    float* wbuf = (float*)(smem + 4096);                   // overlay on As slot0

    int tid = threadIdx.x;
    int lane = tid & 63;
    int w = tid >> 6;              // 0..15
    int wm = w >> 3, wn = w & 7;   // 2 x 8 wave grid; wave tile 64x64
    long row0 = (long)bm * 128;

    // --- A reg-staging: thread -> row r = tid>>3, k-eighth e8 = tid&7 (16B) ---
    int ar_r = tid >> 3;
    int ar_e = tid & 7;
    const char* gAr = (const char*)A + (row0 + ar_r) * 2048 + ar_e * 16;
    int awr = ar_r * 64 + ((ar_e * 8) ^ (((ar_r >> 1) & 3) << 4));

    // --- B staging: linear LDS dest (wave base + lane*16), pre-swizzled src ---
    int offw = w * 2048 + lane * 16;             // this wave's 2KB of 32KB slot
    const char* gB0;
    const char* gB1;
    {
        int o = offw;
        int r = o >> 6;
        gB0 = (const char*)Wt + r * 1024 + ((o & 63) ^ (((r >> 1) & 3) << 4));
        o = offw + 1024;
        r = o >> 6;
        gB1 = (const char*)Wt + r * 1024 + ((o & 63) ^ (((r >> 1) & 3) << 4));
    }

    // --- fragment read byte offsets (within one slot) ---
    int aoff[4], boff[4];
    int kb = 16 * (lane >> 4);
    #pragma unroll
    for (int mi = 0; mi < 4; ++mi) {
        int ar = wm * 64 + (lane & 15) + mi * 16;
        aoff[mi] = ar * 64 + (kb ^ (((ar >> 1) & 3) << 4));
    }
    #pragma unroll
    for (int ni = 0; ni < 4; ++ni) {
        int br = wn * 64 + (lane & 15) + ni * 16;
        boff[ni] = br * 64 + (kb ^ (((br >> 1) & 3) << 4));
    }

    f32x4 acc[4][4] = {};
    float4v P;

#define GISSUE(t, sI) do {                                                   \
    P = *(const float4v*)(gAr + (t) * 128);                                  \
    char* lb_ = (char*)Bs + (sI) * 32768 + offw;                             \
    gload_lds16(gB0 + (t) * 64, lb_);                                        \
    gload_lds16(gB1 + (t) * 64, lb_ + 1024);                                 \
} while (0)

#define CVTW(sW) do {                                                        \
    union { unsigned int u[2]; unsigned long long ll; } pk_;                 \
    pk_.u[0] = (unsigned int)f2bf(P[0]) | ((unsigned int)f2bf(P[1]) << 16);  \
    pk_.u[1] = (unsigned int)f2bf(P[2]) | ((unsigned int)f2bf(P[3]) << 16);  \
    *(unsigned long long*)((char*)As + (sW) * 8192 + awr) = pk_.ll;          \
} while (0)

#define KCOMP(sC) do {                                                       \
    const char* as_ = (const char*)As + (sC) * 8192;                         \
    const char* bs_ = (const char*)Bs + (sC) * 32768;                        \
    short8 af_[4];                                                           \
    _Pragma("unroll")                                                        \
    for (int mi = 0; mi < 4; ++mi) af_[mi] = *(const short8*)(as_ + aoff[mi]); \
    _Pragma("unroll")                                                        \
    for (int ni = 0; ni < 4; ++ni) {                                         \
        short8 bf_ = *(const short8*)(bs_ + boff[ni]);                       \
        _Pragma("unroll")                                                    \
        for (int mi = 0; mi < 4; ++mi)                                       \
            acc[mi][ni] = __builtin_amdgcn_mfma_f32_16x16x32_bf16(af_[mi], bf_, acc[mi][ni], 0, 0, 0); \
    }                                                                        \
} while (0)

#define KITER(t) do {                                                        \
    GISSUE((t) + 1, ((t) + 1) & 1);                                          \
    KCOMP((t) & 1);                                                          \
    asm volatile("s_waitcnt vmcnt(2)" ::: "memory");                         \
    CVTW(((t) + 1) & 1);                                                     \
    asm volatile("s_waitcnt vmcnt(0) lgkmcnt(0)" ::: "memory");              \
    __builtin_amdgcn_s_barrier();                                            \
    asm volatile("" ::: "memory");                                           \
} while (0)

    // prologue: stage K-step 0 into slot 0
    GISSUE(0, 0);
    asm volatile("s_waitcnt vmcnt(2)" ::: "memory");   // A regs landed
    CVTW(0);
    asm volatile("s_waitcnt vmcnt(0) lgkmcnt(0)" ::: "memory");
    __builtin_amdgcn_s_barrier();
    asm volatile("" ::: "memory");

    KITER(0);  KITER(1);  KITER(2);  KITER(3);
    KITER(4);  KITER(5);  KITER(6);  KITER(7);
    KITER(8);  KITER(9);  KITER(10); KITER(11);
    KITER(12); KITER(13); KITER(14);
    KCOMP(1);                                          // t = 15 (As slot1 + Bs only)

    // epilogue: u = tanh(acc + qc), per-wave 64-col partial via 16-lane
    // reduce, then in-block reduce over the 8 wn waves in LDS (overlaid).
    const float* qcb = qc + b * 512;
    float vcol[4], qcol[4];
    #pragma unroll
    for (int ni = 0; ni < 4; ++ni) {
        int c = wn * 64 + ni * 16 + (lane & 15);
        vcol[ni] = v[c];
        qcol[ni] = qcb[c];
    }
    #pragma unroll
    for (int mi = 0; mi < 4; ++mi) {
        #pragma unroll
        for (int j2 = 0; j2 < 4; ++j2) {
            float s = 0.f;
            #pragma unroll
            for (int ni = 0; ni < 4; ++ni) {
                float xx = acc[mi][ni][j2] + qcol[ni];
                float e2 = __expf(2.0f * xx);
                float tt = 1.0f - 2.0f * __builtin_amdgcn_rcpf(e2 + 1.0f);
                s += tt * vcol[ni];
            }
            s += __shfl_xor(s, 1);
            s += __shfl_xor(s, 2);
            s += __shfl_xor(s, 4);
            s += __shfl_xor(s, 8);
            if ((lane & 15) == 0)
                lred[wm * 64 + mi * 16 + 4 * (lane >> 4) + j2][wn] = s;
        }
    }
    __syncthreads();

    // fused: w = exp(logit) (0 beyond length), raw w -> att, sum -> S[b]
    if (tid < 128) {
        float lg = 0.f;
        #pragma unroll
        for (int q = 0; q < 8; ++q) lg += lred[tid][q];
        float wf = (l0 + tid < len) ? __expf(lg) : 0.f;
        att[row0 + tid] = wf;
        wbuf[tid] = wf;
        float s = wf;
        #pragma unroll
        for (int m = 32; m; m >>= 1) s += __shfl_xor(s, m);
        if ((tid & 63) == 0) atomicAdd(&S[b], s);
    }
    __syncthreads();

    // fused ctx: thread covers e = tid&511, l-half = tid>>9 (L2-hot A tile)
    {
        int e = tid & 511;
        int lh = tid >> 9;                 // 0 or 1
        const float* encb = A + (row0 + lh * 64) * 512 + e;
        const float* wb = &wbuf[lh * 64];
        float c = 0.f;
        #pragma unroll 4
        for (int l = 0; l < 64; ++l)
            c += wb[l] * encb[l * 512];
        atomicAdd(&ctxraw[b * 512 + e], c);
    }
}

// normalize: att[l] = (l<len) ? w[l]/S[b] : 0 ; ctx = ctxraw/S[b]
__global__ void norm_kernel(const float* __restrict__ S, const int* __restrict__ length,
                            const float* __restrict__ ctxraw,
                            float* __restrict__ att, float* __restrict__ ctx) {
    int b = blockIdx.x;
    int tid = threadIdx.x;     // 256
    float inv = 1.0f / S[b];
    ctx[b * 512 + tid] = ctxraw[b * 512 + tid] * inv;
    ctx[b * 512 + 256 + tid] = ctxraw[b * 512 + 256 + tid] * inv;
    int len = length[b];
    float* ab = att + b * 2048;
    #pragma unroll
    for (int i = 0; i < 8; ++i) {
        int l = tid + i * 256;
        float wv = ab[l];
        ab[l] = (l < len) ? wv * inv : 0.f;
    }
}

extern "C" void kernel_launch(void* const* d_in, const int* in_sizes, int n_in,
                              void* d_out, int out_size, void* d_ws, size_t ws_size,
                              hipStream_t stream) {
    const float* enc    = (const float*)d_in[0];   // [64,2048,512]
    const float* query  = (const float*)d_in[1];   // [64,256]
    const int*   length = (const int*)d_in[2];     // [64]
    const float* W1     = (const float*)d_in[3];   // [768,512]
    const float* b1     = (const float*)d_in[4];   // [512]
    const float* v      = (const float*)d_in[5];   // [512]

    float* out = (float*)d_out;
    float* ctx = out;                // [64,512]
    float* att = out + 64 * 512;     // [64,2048]

    char* ws = (char*)d_ws;
    float* qc          = (float*)ws;                               // 128KB
    unsigned short* Wt = (unsigned short*)(ws + 64 * 512 * 4);     // 512KB
    float* ctxraw      = (float*)(ws + 64 * 512 * 4 + 512 * 1024); // 128KB
    float* S           = (float*)(ws + 64 * 512 * 4 + 512 * 1024 + 64 * 512 * 4); // 256B

    prep_wt_kernel<<<256, 256, 0, stream>>>(W1, Wt);
    prep_qc_kernel<<<64, 256, 0, stream>>>(query, W1, b1, qc, ctxraw, S);

    gemm_fused_kernel<<<1024, 1024, 0, stream>>>(enc, Wt, qc, v, length, att, ctxraw, S);

    norm_kernel<<<64, 256, 0, stream>>>(S, length, ctxraw, att, ctx);
}

// Round 20
// 139.262 us; speedup vs baseline: 4.8286x; 1.0046x over previous
//
#include <hip/hip_runtime.h>

typedef __attribute__((ext_vector_type(4))) float float4v;
typedef __attribute__((ext_vector_type(2))) float float2v;
typedef __attribute__((ext_vector_type(8))) short short8;
typedef __attribute__((ext_vector_type(4))) float f32x4;

#define NEGV (-1000000000.0f)

// B=64, L=2048, E=512, Q=256; M = 131072, K = 512, N = 512
#define MTOT (64 * 2048)

__device__ __forceinline__ unsigned short f2bf(float f) {
    unsigned int u = __float_as_uint(f);
    u += 0x7fffu + ((u >> 16) & 1u);   // RNE round to bf16
    return (unsigned short)(u >> 16);
}

// async global->LDS, 16B per lane; LDS dest = wave-uniform base + lane*16
__device__ __forceinline__ void gload_lds16(const void* g, void* l) {
    __builtin_amdgcn_global_load_lds(
        (__attribute__((address_space(1))) unsigned int*)(unsigned long long)(g),
        (__attribute__((address_space(3))) unsigned int*)(unsigned int)(unsigned long long)(l),
        16, 0, 0);
}

// Wt[e][c] = bf16(W1[c][e]) via LDS 32x32 tile transpose.
__global__ __launch_bounds__(256)
void prep_wt_kernel(const float* __restrict__ W1, unsigned short* __restrict__ Wt) {
    __shared__ float t[32][33];
    int bx = blockIdx.x & 15;    // c tile
    int by = blockIdx.x >> 4;    // e tile
    int tx = threadIdx.x & 31;
    int ty = threadIdx.x >> 5;   // 0..7
    #pragma unroll
    for (int i = 0; i < 4; ++i)
        t[ty + 8 * i][tx] = W1[(bx * 32 + ty + 8 * i) * 512 + by * 32 + tx];
    __syncthreads();
    #pragma unroll
    for (int i = 0; i < 4; ++i)
        Wt[(by * 32 + ty + 8 * i) * 512 + bx * 32 + tx] = f2bf(t[tx][ty + 8 * i]);
}

// qc[b][e] = b1[e] + sum_q query[b][q] * W1[512+q][e]; also zeroes ctxraw/S.
__global__ void prep_qc_kernel(const float* __restrict__ query, const float* __restrict__ W1,
                               const float* __restrict__ b1, float* __restrict__ qc,
                               float* __restrict__ ctxraw, float* __restrict__ S) {
    int b = blockIdx.x;
    int e = threadIdx.x;           // 256 threads -> cols e and e+256
    ctxraw[b * 512 + e] = 0.f;
    ctxraw[b * 512 + 256 + e] = 0.f;
    if (e == 0) S[b] = 0.f;
    float acc0 = b1[e];
    float acc1 = b1[e + 256];
    const float* w = W1 + 512 * 512;
    #pragma unroll 8
    for (int q = 0; q < 256; ++q) {
        float qv = query[b * 256 + q];
        acc0 += qv * w[q * 512 + e];
        acc1 += qv * w[q * 512 + e + 256];
    }
    qc[b * 512 + e] = acc0;
    qc[b * 512 + e + 256] = acc1;
}

// R17's fused gemm with LDS cut to 72KB so 2 blocks/CU REALLY fit (R19's
// 80KB did not co-schedule: occupancy stayed 25%). Cut = single-buffered A
// slot (8KB); the WAR hazard is fenced by one extra barrier between
// KCOMP(t) (last As(t) reader) and CVTW (As(t+1) writer). B stays dbuf'd,
// pipeline depth unchanged. lred/wbuf overlay on Bs slot-0 (dead in final
// KCOMP which reads slot 1, and in epilogue). 2 x 16 waves x 64 VGPR =
// full register file; one block's drain overlaps the sibling's compute.
__global__ __launch_bounds__(1024)
void gemm_fused_kernel(const float* __restrict__ A,             // encoded [M][512] f32
                       const unsigned short* __restrict__ Wt,   // [512 n][512 k] bf16
                       const float* __restrict__ qc,            // [64][512]
                       const float* __restrict__ v,             // [512]
                       const int* __restrict__ length,          // [64]
                       float* __restrict__ att,                 // [M] raw w out
                       float* __restrict__ ctxraw,              // [64][512] accum
                       float* __restrict__ S)                   // [64] sum accum
{
    int bm = blockIdx.x;           // 0..1023 row tile
    int b = bm >> 4;
    int len = length[b];
    int l0 = (bm & 15) * 128;
    if (l0 >= len) return;         // fully-masked tile

    __shared__ char smem[73728];   // 72KB: 2 blocks/CU (144KB < 160KB)
    unsigned short* As = (unsigned short*)smem;            // 1 x 8 KB (single)
    unsigned short* Bs = (unsigned short*)(smem + 8192);   // 2 x 32 KB
    float (*lred)[8] = (float(*)[8])(smem + 8192);         // overlay on Bs slot0
    float* wbuf = (float*)(smem + 8192 + 4096);            // overlay on Bs slot0

    int tid = threadIdx.x;
    int lane = tid & 63;
    int w = tid >> 6;              // 0..15
    int wm = w >> 3, wn = w & 7;   // 2 x 8 wave grid; wave tile 64x64
    long row0 = (long)bm * 128;

    // --- A reg-staging: thread -> row r = tid>>3, k-eighth e8 = tid&7 (16B) ---
    int ar_r = tid >> 3;
    int ar_e = tid & 7;
    const char* gAr = (const char*)A + (row0 + ar_r) * 2048 + ar_e * 16;
    int awr = ar_r * 64 + ((ar_e * 8) ^ (((ar_r >> 1) & 3) << 4));

    // --- B staging: linear LDS dest (wave base + lane*16), pre-swizzled src ---
    int offw = w * 2048 + lane * 16;             // this wave's 2KB of 32KB slot
    const char* gB0;
    const char* gB1;
    {
        int o = offw;
        int r = o >> 6;
        gB0 = (const char*)Wt + r * 1024 + ((o & 63) ^ (((r >> 1) & 3) << 4));
        o = offw + 1024;
        r = o >> 6;
        gB1 = (const char*)Wt + r * 1024 + ((o & 63) ^ (((r >> 1) & 3) << 4));
    }

    // --- fragment read byte offsets ---
    int aoff[4], boff[4];
    int kb = 16 * (lane >> 4);
    #pragma unroll
    for (int mi = 0; mi < 4; ++mi) {
        int ar = wm * 64 + (lane & 15) + mi * 16;
        aoff[mi] = ar * 64 + (kb ^ (((ar >> 1) & 3) << 4));
    }
    #pragma unroll
    for (int ni = 0; ni < 4; ++ni) {
        int br = wn * 64 + (lane & 15) + ni * 16;
        boff[ni] = br * 64 + (kb ^ (((br >> 1) & 3) << 4));
    }

    f32x4 acc[4][4] = {};
    float4v P;

#define GISSUE(t, sI) do {                                                   \
    P = *(const float4v*)(gAr + (t) * 128);                                  \
    char* lb_ = (char*)Bs + (sI) * 32768 + offw;                             \
    gload_lds16(gB0 + (t) * 64, lb_);                                        \
    gload_lds16(gB1 + (t) * 64, lb_ + 1024);                                 \
} while (0)

#define CVTW() do {                                                          \
    union { unsigned int u[2]; unsigned long long ll; } pk_;                 \
    pk_.u[0] = (unsigned int)f2bf(P[0]) | ((unsigned int)f2bf(P[1]) << 16);  \
    pk_.u[1] = (unsigned int)f2bf(P[2]) | ((unsigned int)f2bf(P[3]) << 16);  \
    *(unsigned long long*)((char*)As + awr) = pk_.ll;                        \
} while (0)

#define KCOMP(sC) do {                                                       \
    const char* as_ = (const char*)As;                                       \
    const char* bs_ = (const char*)Bs + (sC) * 32768;                        \
    short8 af_[4];                                                           \
    _Pragma("unroll")                                                        \
    for (int mi = 0; mi < 4; ++mi) af_[mi] = *(const short8*)(as_ + aoff[mi]); \
    _Pragma("unroll")                                                        \
    for (int ni = 0; ni < 4; ++ni) {                                         \
        short8 bf_ = *(const short8*)(bs_ + boff[ni]);                       \
        _Pragma("unroll")                                                    \
        for (int mi = 0; mi < 4; ++mi)                                       \
            acc[mi][ni] = __builtin_amdgcn_mfma_f32_16x16x32_bf16(af_[mi], bf_, acc[mi][ni], 0, 0, 0); \
    }                                                                        \
} while (0)

// GISSUE(t+1) -> KCOMP(t) -> barrier (As(t) readers done) -> vmcnt(2) (A regs
// landed; 2 B-loads still in flight) -> CVTW(As(t+1)) -> vmcnt(0)+lgkm(0)
// (B(t+1) staged, As write visible) -> barrier.
#define KITER(t) do {                                                        \
    GISSUE((t) + 1, ((t) + 1) & 1);                                          \
    KCOMP((t) & 1);                                                          \
    asm volatile("" ::: "memory");                                           \
    __builtin_amdgcn_s_barrier();                                            \
    asm volatile("s_waitcnt vmcnt(2)" ::: "memory");                         \
    CVTW();                                                                  \
    asm volatile("s_waitcnt vmcnt(0) lgkmcnt(0)" ::: "memory");              \
    __builtin_amdgcn_s_barrier();                                            \
    asm volatile("" ::: "memory");                                           \
} while (0)

    // prologue: stage step 0 (B->slot0, A->As)
    GISSUE(0, 0);
    asm volatile("s_waitcnt vmcnt(2)" ::: "memory");   // A regs landed
    CVTW();
    asm volatile("s_waitcnt vmcnt(0) lgkmcnt(0)" ::: "memory");
    __builtin_amdgcn_s_barrier();
    asm volatile("" ::: "memory");

    KITER(0);  KITER(1);  KITER(2);  KITER(3);
    KITER(4);  KITER(5);  KITER(6);  KITER(7);
    KITER(8);  KITER(9);  KITER(10); KITER(11);
    KITER(12); KITER(13); KITER(14);
    KCOMP(1);                                          // t = 15 (As + Bs slot1)

    // epilogue: u = tanh(acc + qc), per-wave 64-col partial via 16-lane
    // reduce, then in-block reduce over the 8 wn waves (lred on Bs slot0 —
    // not touched by any wave still inside KCOMP(15), which reads slot1+As).
    const float* qcb = qc + b * 512;
    float vcol[4], qcol[4];
    #pragma unroll
    for (int ni = 0; ni < 4; ++ni) {
        int c = wn * 64 + ni * 16 + (lane & 15);
        vcol[ni] = v[c];
        qcol[ni] = qcb[c];
    }
    #pragma unroll
    for (int mi = 0; mi < 4; ++mi) {
        #pragma unroll
        for (int j2 = 0; j2 < 4; ++j2) {
            float s = 0.f;
            #pragma unroll
            for (int ni = 0; ni < 4; ++ni) {
                float xx = acc[mi][ni][j2] + qcol[ni];
                float e2 = __expf(2.0f * xx);
                float tt = 1.0f - 2.0f * __builtin_amdgcn_rcpf(e2 + 1.0f);
                s += tt * vcol[ni];
            }
            s += __shfl_xor(s, 1);
            s += __shfl_xor(s, 2);
            s += __shfl_xor(s, 4);
            s += __shfl_xor(s, 8);
            if ((lane & 15) == 0)
                lred[wm * 64 + mi * 16 + 4 * (lane >> 4) + j2][wn] = s;
        }
    }
    __syncthreads();

    // fused: w = exp(logit) (0 beyond length), raw w -> att, sum -> S[b]
    if (tid < 128) {
        float lg = 0.f;
        #pragma unroll
        for (int q = 0; q < 8; ++q) lg += lred[tid][q];
        float wf = (l0 + tid < len) ? __expf(lg) : 0.f;
        att[row0 + tid] = wf;
        wbuf[tid] = wf;
        float s = wf;
        #pragma unroll
        for (int m = 32; m; m >>= 1) s += __shfl_xor(s, m);
        if ((tid & 63) == 0) atomicAdd(&S[b], s);
    }
    __syncthreads();

    // fused ctx: thread covers e = tid&511, l-half = tid>>9 (L2-hot A tile)
    {
        int e = tid & 511;
        int lh = tid >> 9;                 // 0 or 1
        const float* encb = A + (row0 + lh * 64) * 512 + e;
        const float* wb = &wbuf[lh * 64];
        float c = 0.f;
        #pragma unroll 4
        for (int l = 0; l < 64; ++l)
            c += wb[l] * encb[l * 512];
        atomicAdd(&ctxraw[b * 512 + e], c);
    }
}

// normalize: att[l] = (l<len) ? w[l]/S[b] : 0 ; ctx = ctxraw/S[b]
__global__ void norm_kernel(const float* __restrict__ S, const int* __restrict__ length,
                            const float* __restrict__ ctxraw,
                            float* __restrict__ att, float* __restrict__ ctx) {
    int b = blockIdx.x;
    int tid = threadIdx.x;     // 256
    float inv = 1.0f / S[b];
    ctx[b * 512 + tid] = ctxraw[b * 512 + tid] * inv;
    ctx[b * 512 + 256 + tid] = ctxraw[b * 512 + 256 + tid] * inv;
    int len = length[b];
    float* ab = att + b * 2048;
    #pragma unroll
    for (int i = 0; i < 8; ++i) {
        int l = tid + i * 256;
        float wv = ab[l];
        ab[l] = (l < len) ? wv * inv : 0.f;
    }
}

extern "C" void kernel_launch(void* const* d_in, const int* in_sizes, int n_in,
                              void* d_out, int out_size, void* d_ws, size_t ws_size,
                              hipStream_t stream) {
    const float* enc    = (const float*)d_in[0];   // [64,2048,512]
    const float* query  = (const float*)d_in[1];   // [64,256]
    const int*   length = (const int*)d_in[2];     // [64]
    const float* W1     = (const float*)d_in[3];   // [768,512]
    const float* b1     = (const float*)d_in[4];   // [512]
    const float* v      = (const float*)d_in[5];   // [512]

    float* out = (float*)d_out;
    float* ctx = out;                // [64,512]
    float* att = out + 64 * 512;     // [64,2048]

    char* ws = (char*)d_ws;
    float* qc          = (float*)ws;                               // 128KB
    unsigned short* Wt = (unsigned short*)(ws + 64 * 512 * 4);     // 512KB
    float* ctxraw      = (float*)(ws + 64 * 512 * 4 + 512 * 1024); // 128KB
    float* S           = (float*)(ws + 64 * 512 * 4 + 512 * 1024 + 64 * 512 * 4); // 256B

    prep_wt_kernel<<<256, 256, 0, stream>>>(W1, Wt);
    prep_qc_kernel<<<64, 256, 0, stream>>>(query, W1, b1, qc, ctxraw, S);

    gemm_fused_kernel<<<1024, 1024, 0, stream>>>(enc, Wt, qc, v, length, att, ctxraw, S);

    norm_kernel<<<64, 256, 0, stream>>>(S, length, ctxraw, att, ctx);
}